// Round 1
// baseline (2466.732 us; speedup 1.0000x reference)
//
#include <hip/hip_runtime.h>
#include <cmath>
#include <cstdint>

#define D_MODEL 512
#define NH 8
#define DH 64

static inline int ceil_div(int a, int b) { return (a + b - 1) / b; }

// ---------------- threefry2x32 (JAX-exact) ----------------
#define TF_ROTL(x, r) (((x) << (r)) | ((x) >> (32 - (r))))

__host__ __device__ inline void threefry2x32(uint32_t k0, uint32_t k1,
                                             uint32_t x0, uint32_t x1,
                                             uint32_t* o0, uint32_t* o1) {
  uint32_t ks2 = k0 ^ k1 ^ 0x1BD11BDAu;
  x0 += k0; x1 += k1;
#define TF_R4(a, b, c, d)                                    \
  x0 += x1; x1 = TF_ROTL(x1, a); x1 ^= x0;                   \
  x0 += x1; x1 = TF_ROTL(x1, b); x1 ^= x0;                   \
  x0 += x1; x1 = TF_ROTL(x1, c); x1 ^= x0;                   \
  x0 += x1; x1 = TF_ROTL(x1, d); x1 ^= x0;
  TF_R4(13, 15, 26, 6);  x0 += k1;  x1 += ks2 + 1u;
  TF_R4(17, 29, 16, 24); x0 += ks2; x1 += k0 + 2u;
  TF_R4(13, 15, 26, 6);  x0 += k0;  x1 += k1 + 3u;
  TF_R4(17, 29, 16, 24); x0 += k1;  x1 += ks2 + 4u;
  TF_R4(13, 15, 26, 6);  x0 += ks2; x1 += k0 + 5u;
#undef TF_R4
  *o0 = x0; *o1 = x1;
}

// idx[n] for n in [0, L*U): partitionable random_bits with 64-bit counter n
// (hi=0, lo=n), folded hi^lo, masked to L-1 (L is a power of two so the
// randint multiplier is 0 and only lower_bits matter).
__global__ void idx_kernel(int* __restrict__ idx, int L, int U,
                           uint32_t k0, uint32_t k1) {
  int n = blockIdx.x * 256 + threadIdx.x;
  if (n >= L * U) return;
  uint32_t o0, o1;
  threefry2x32(k0, k1, 0u, (uint32_t)n, &o0, &o1);
  idx[n] = (int)((o0 ^ o1) & (uint32_t)(L - 1));
}

// ---------------- embedding: circular conv (C=2,K=3) + pos encoding -------
__global__ __launch_bounds__(256) void embed_kernel(
    const float* __restrict__ x_enc, const float* __restrict__ emb_w,
    float* __restrict__ x, int B, int L) {
  int i = blockIdx.x * 256 + threadIdx.x;
  int total = B * L * D_MODEL;
  if (i >= total) return;
  int d = i % D_MODEL;
  int l = (i / D_MODEL) % L;
  int b = i / (D_MODEL * L);
  int lm = (l == 0) ? (L - 1) : (l - 1);
  int lp = (l == L - 1) ? 0 : (l + 1);
  const float* w = emb_w + d * 6;
  const float* xb = x_enc + (size_t)b * L * 2;
  float acc = 0.f;
  acc += xb[lm * 2 + 0] * w[0] + xb[l * 2 + 0] * w[1] + xb[lp * 2 + 0] * w[2];
  acc += xb[lm * 2 + 1] * w[3] + xb[l * 2 + 1] * w[4] + xb[lp * 2 + 1] * w[5];
  // pos encoding: div = exp(2j * (-ln(10000)/512)), fp32 like the reference
  int j = d >> 1;
  const float coef = -0.017988946039015985f;  // -ln(10000)/512
  float div = expf((float)(2 * j) * coef);
  float ang = (float)l * div;
  float pe = (d & 1) ? cosf(ang) : sinf(ang);
  x[i] = acc + pe;
}

// ---------------- layer norm over D=512 ----------------
__global__ __launch_bounds__(256) void ln_kernel(
    const float* __restrict__ in, const float* __restrict__ g,
    const float* __restrict__ b, float* __restrict__ out) {
  int row = blockIdx.x;
  int t = threadIdx.x;
  const float* xr = in + (size_t)row * D_MODEL;
  float v0 = xr[t], v1 = xr[t + 256];
  __shared__ float red[256];
  red[t] = v0 + v1;
  __syncthreads();
  for (int s = 128; s > 0; s >>= 1) { if (t < s) red[t] += red[t + s]; __syncthreads(); }
  float mean = red[0] * (1.0f / 512.0f);
  __syncthreads();
  float d0 = v0 - mean, d1 = v1 - mean;
  red[t] = d0 * d0 + d1 * d1;
  __syncthreads();
  for (int s = 128; s > 0; s >>= 1) { if (t < s) red[t] += red[t + s]; __syncthreads(); }
  float var = red[0] * (1.0f / 512.0f);
  float rstd = 1.0f / sqrtf(var + 1e-5f);
  float* outr = out + (size_t)row * D_MODEL;
  outr[t]       = d0 * rstd * g[t]       + b[t];
  outr[t + 256] = d1 * rstd * g[t + 256] + b[t + 256];
}

// ---------------- fp32 tiled GEMM: C = A(MxK) @ Bt(NxK)^T + bias ----------
// MODE 0: +bias   1: gelu(+bias)   2: +bias +R   3: elu((+bias)*scl*g + bb)
#define BM 64
#define BN 64
#define BK 16
#define PADR 4

template <int MODE>
__global__ __launch_bounds__(256) void gemm_kernel(
    const float* __restrict__ A, const float* __restrict__ Bt,
    const float* __restrict__ bias, const float* __restrict__ R,
    const float* __restrict__ gvec, const float* __restrict__ bvec,
    float* __restrict__ C, int M, int N, int K, float scl) {
  __shared__ float As[BK][BM + PADR];
  __shared__ float Bs[BK][BN + PADR];
  const int bm = blockIdx.y * BM;
  const int bn = blockIdx.x * BN;
  const int tid = threadIdx.x;
  const int tx = tid & 15, ty = tid >> 4;
  const int lr = tid >> 2;
  const int lc = (tid & 3) << 2;
  const float* Aptr = A + (size_t)(bm + lr) * K + lc;
  const float* Bptr = Bt + (size_t)(bn + lr) * K + lc;
  float acc[4][4] = {};
  for (int k0 = 0; k0 < K; k0 += BK) {
    float4 av = *(const float4*)(Aptr + k0);
    float4 bv = *(const float4*)(Bptr + k0);
    As[lc + 0][lr] = av.x; As[lc + 1][lr] = av.y;
    As[lc + 2][lr] = av.z; As[lc + 3][lr] = av.w;
    Bs[lc + 0][lr] = bv.x; Bs[lc + 1][lr] = bv.y;
    Bs[lc + 2][lr] = bv.z; Bs[lc + 3][lr] = bv.w;
    __syncthreads();
#pragma unroll
    for (int kk = 0; kk < BK; ++kk) {
      float4 a4 = *(const float4*)&As[kk][ty << 2];
      float4 b4 = *(const float4*)&Bs[kk][tx << 2];
      float ar[4] = {a4.x, a4.y, a4.z, a4.w};
      float br[4] = {b4.x, b4.y, b4.z, b4.w};
#pragma unroll
      for (int i = 0; i < 4; ++i)
#pragma unroll
        for (int j = 0; j < 4; ++j) acc[i][j] += ar[i] * br[j];
    }
    __syncthreads();
  }
#pragma unroll
  for (int i = 0; i < 4; ++i) {
    int row = bm + (ty << 2) + i;
    float* Cr = C + (size_t)row * N;
    const float* Rr = (MODE == 2) ? (R + (size_t)row * N) : nullptr;
#pragma unroll
    for (int j = 0; j < 4; ++j) {
      int col = bn + (tx << 2) + j;
      float v = acc[i][j] + bias[col];
      if (MODE == 1) {
        v = 0.5f * v * (1.0f + erff(v * 0.7071067811865475f));
      } else if (MODE == 2) {
        v += Rr[col];
      } else if (MODE == 3) {
        v = v * scl * gvec[col] + bvec[col];
        v = (v > 0.f) ? v : expm1f(v);
      }
      Cr[col] = v;
    }
  }
}

// ---------------- sparse measurement M = max_u(QK) - sum_u(QK)/L ----------
__global__ __launch_bounds__(256) void sparse_m_kernel(
    const float* __restrict__ Q, const float* __restrict__ Km,
    const int* __restrict__ idx, float* __restrict__ Mout, int B, int L,
    int U) {
  int wid = (blockIdx.x * 256 + threadIdx.x) >> 6;
  int lane = threadIdx.x & 63;
  int total = B * NH * L;
  if (wid >= total) return;
  int l = wid % L;
  int bh = wid / L;
  int b = bh / NH, h = bh % NH;
  float qv = Q[((size_t)(b * L + l)) * D_MODEL + h * DH + lane];
  const float* Kbase = Km + (size_t)b * L * D_MODEL + h * DH;
  float maxv = -INFINITY, sumv = 0.f;
  for (int u = 0; u < U; ++u) {
    int ki = idx[l * U + u];
    float p = qv * Kbase[(size_t)ki * D_MODEL + lane];
#pragma unroll
    for (int m = 32; m; m >>= 1) p += __shfl_xor(p, m);
    maxv = fmaxf(maxv, p);
    sumv += p;
  }
  if (lane == 0) Mout[wid] = maxv - sumv / (float)L;
}

// ---------------- top-k (stable: ties -> lower index), u <= 40 ------------
__global__ __launch_bounds__(256) void topk_kernel(
    const float* __restrict__ Mv, int* __restrict__ Mtop, int L, int u) {
  __shared__ float sv[2048];
  __shared__ float rv[256];
  __shared__ int ri[256];
  int bh = blockIdx.x;
  int t = threadIdx.x;
  for (int l = t; l < L; l += 256) sv[l] = Mv[(size_t)bh * L + l];
  __syncthreads();
  for (int it = 0; it < u; ++it) {
    float bv = -INFINITY;
    int bi = 0x7fffffff;
    for (int l = t; l < L; l += 256) {
      float v = sv[l];
      if (v > bv || (v == bv && l < bi)) { bv = v; bi = l; }
    }
    rv[t] = bv; ri[t] = bi;
    __syncthreads();
    for (int s = 128; s > 0; s >>= 1) {
      if (t < s) {
        float v2 = rv[t + s]; int i2 = ri[t + s];
        if (v2 > rv[t] || (v2 == rv[t] && i2 < ri[t])) { rv[t] = v2; ri[t] = i2; }
      }
      __syncthreads();
    }
    if (t == 0) { Mtop[bh * u + it] = ri[0]; sv[ri[0]] = -INFINITY; }
    __syncthreads();
  }
}

// ---------------- mean of V over L per (b,h) ----------------
__global__ __launch_bounds__(256) void vmean_kernel(
    const float* __restrict__ V, float* __restrict__ vmean, int B, int L) {
  int bh = blockIdx.x;
  int b = bh / NH, h = bh % NH;
  int t = threadIdx.x;
  int e = t & 63, part = t >> 6;
  const float* base = V + (size_t)b * L * D_MODEL + h * DH + e;
  float s = 0.f;
  for (int l = part; l < L; l += 4) s += base[(size_t)l * D_MODEL];
  __shared__ float red[4][64];
  red[part][e] = s;
  __syncthreads();
  if (part == 0) {
    float tot = red[0][e] + red[1][e] + red[2][e] + red[3][e];
    vmean[bh * DH + e] = tot / (float)L;
  }
}

__global__ void fill_ctx_kernel(const float* __restrict__ vmean,
                                float* __restrict__ O, int B, int L) {
  int i = blockIdx.x * 256 + threadIdx.x;
  int total = B * L * D_MODEL;
  if (i >= total) return;
  int dcol = i % D_MODEL;
  int b = i / (D_MODEL * L);
  O[i] = vmean[(b * NH + (dcol >> 6)) * DH + (dcol & 63)];
}

// ---------------- full attention for the u selected query rows ------------
__global__ __launch_bounds__(256) void attn_kernel(
    const float* __restrict__ Q, const float* __restrict__ Km,
    const float* __restrict__ V, const int* __restrict__ Mtop,
    float* __restrict__ O, int B, int L, int u) {
  __shared__ float p[2048];
  __shared__ float qs[DH];
  __shared__ float red[256];
  __shared__ float pv[4][DH];
  int j = blockIdx.x;
  int bh = blockIdx.y;
  int b = bh / NH, h = bh % NH;
  int l = Mtop[bh * u + j];
  int t = threadIdx.x;
  if (t < DH) qs[t] = Q[((size_t)(b * L + l)) * D_MODEL + h * DH + t];
  __syncthreads();
  const float* Kb = Km + (size_t)b * L * D_MODEL + h * DH;
  float lmax = -INFINITY;
  for (int lp = t; lp < L; lp += 256) {
    const float* kr = Kb + (size_t)lp * D_MODEL;
    float s = 0.f;
#pragma unroll
    for (int e = 0; e < DH; ++e) s += qs[e] * kr[e];
    s *= 0.125f;  // 1/sqrt(64)
    p[lp] = s;
    lmax = fmaxf(lmax, s);
  }
  red[t] = lmax;
  __syncthreads();
  for (int s = 128; s > 0; s >>= 1) { if (t < s) red[t] = fmaxf(red[t], red[t + s]); __syncthreads(); }
  float gmax = red[0];
  __syncthreads();
  float lsum = 0.f;
  for (int lp = t; lp < L; lp += 256) {
    float e = expf(p[lp] - gmax);
    p[lp] = e;
    lsum += e;
  }
  red[t] = lsum;
  __syncthreads();
  for (int s = 128; s > 0; s >>= 1) { if (t < s) red[t] += red[t + s]; __syncthreads(); }
  float inv = 1.0f / red[0];
  __syncthreads();
  int e = t & 63, part = t >> 6;
  const float* Vb = V + (size_t)b * L * D_MODEL + h * DH + e;
  float acc = 0.f;
  for (int lp = part; lp < L; lp += 4) acc += p[lp] * Vb[(size_t)lp * D_MODEL];
  pv[part][e] = acc;
  __syncthreads();
  if (part == 0) {
    float tot = (pv[0][e] + pv[1][e] + pv[2][e] + pv[3][e]) * inv;
    O[((size_t)(b * L + l)) * D_MODEL + h * DH + e] = tot;
  }
}

// ---------------- im2col for circular conv (K=3) over D=512 channels ------
__global__ void im2col_kernel(const float* __restrict__ X,
                              float* __restrict__ Y, int B, int L) {
  int i = blockIdx.x * 256 + threadIdx.x;
  int total = B * L * 1536;
  if (i >= total) return;
  int ck = i % 1536;
  int l = (i / 1536) % L;
  int b = i / (1536 * L);
  int c = ck / 3, k = ck % 3;
  int lm = l + k - 1;
  if (lm < 0) lm += L;
  else if (lm >= L) lm -= L;
  Y[i] = X[((size_t)(b * L + lm)) * D_MODEL + c];
}

// ---------------- maxpool k=3 s=2, one -inf pad each side -----------------
__global__ void maxpool_kernel(const float* __restrict__ Y,
                               float* __restrict__ X, int B, int L) {
  int Lo = L / 2;
  int i = blockIdx.x * 256 + threadIdx.x;
  int total = B * Lo * D_MODEL;
  if (i >= total) return;
  int d = i % D_MODEL;
  int lp = (i / D_MODEL) % Lo;
  int b = i / (D_MODEL * Lo);
  int l0 = 2 * lp - 1;
  float m = -INFINITY;
#pragma unroll
  for (int k = 0; k < 3; ++k) {
    int l = l0 + k;
    if (l >= 0 && l < L) m = fmaxf(m, Y[((size_t)(b * L + l)) * D_MODEL + d]);
  }
  X[i] = m;
}

// ==========================================================================
extern "C" void kernel_launch(void* const* d_in, const int* in_sizes, int n_in,
                              void* d_out, int out_size, void* d_ws,
                              size_t ws_size, hipStream_t stream) {
  const float* x_enc  = (const float*)d_in[0];
  const float* emb_w  = (const float*)d_in[1];
  const float* Wq     = (const float*)d_in[2];
  const float* bq     = (const float*)d_in[3];
  const float* Wk     = (const float*)d_in[4];
  const float* bk     = (const float*)d_in[5];
  const float* Wv     = (const float*)d_in[6];
  const float* bv     = (const float*)d_in[7];
  const float* Wo     = (const float*)d_in[8];
  const float* bo     = (const float*)d_in[9];
  const float* ln1_g  = (const float*)d_in[10];
  const float* ln1_b  = (const float*)d_in[11];
  const float* ff_w1  = (const float*)d_in[12];
  const float* ff_b1  = (const float*)d_in[13];
  const float* ff_w2  = (const float*)d_in[14];
  const float* ff_b2  = (const float*)d_in[15];
  const float* ln2_g  = (const float*)d_in[16];
  const float* ln2_b  = (const float*)d_in[17];
  const float* cv_w   = (const float*)d_in[18];
  const float* cv_b   = (const float*)d_in[19];
  const float* bn_g   = (const float*)d_in[20];
  const float* bn_b   = (const float*)d_in[21];
  const float* norm_g = (const float*)d_in[22];
  const float* norm_b = (const float*)d_in[23];

  const int B = 4, L0 = 2048, EL = 3;
  const size_t SZ = (size_t)B * 2048 * 512;  // 4,194,304 floats per 16MB buf
  float* ws   = (float*)d_ws;
  float* xbuf = ws;            // current activations (B,L,512)
  float* ebuf = ws + SZ;       // temp / pre-LN
  float* qbuf = ws + 2 * SZ;
  float* kbuf = ws + 3 * SZ;
  float* vbuf = ws + 4 * SZ;
  float* obuf = ws + 5 * SZ;
  float* im2c = qbuf;          // aliases q..v (48MB); q/k/v dead at conv time
  float* sm   = ws + 6 * SZ;
  int*   d_idx   = (int*)sm;                           // <= 81920 ints
  float* d_M     = sm + 81920;                         // <= 65536 floats
  int*   d_Mtop  = (int*)(sm + 81920 + 65536);         // <= 1280 ints
  float* d_vmean = sm + 81920 + 65536 + 1280;          // 2048 floats

  const float inv_s = 1.0f / sqrtf(1.0f + 1e-5f);

  // embedding
  embed_kernel<<<ceil_div(B * L0 * D_MODEL, 256), 256, 0, stream>>>(
      x_enc, emb_w, xbuf, B, L0);

  int L = L0;
  for (int i = 0; i < EL; ++i) {
    const int M_ = B * L;
    int c = 5 * (int)ceil(log((double)L));
    int U = c < L ? c : L;  // U_part == u here (c < L always)
    const float* Wq_i = Wq + (size_t)i * 512 * 512;
    const float* Wk_i = Wk + (size_t)i * 512 * 512;
    const float* Wv_i = Wv + (size_t)i * 512 * 512;
    const float* Wo_i = Wo + (size_t)i * 512 * 512;
    const float* w1_i = ff_w1 + (size_t)i * 512 * 512;
    const float* w2_i = ff_w2 + (size_t)i * 512 * 512;
    dim3 gg(512 / BN, M_ / BM);

    // q, k, v projections
    gemm_kernel<0><<<gg, 256, 0, stream>>>(xbuf, Wq_i, bq + i * 512, nullptr,
                                           nullptr, nullptr, qbuf, M_, 512, 512, 0.f);
    gemm_kernel<0><<<gg, 256, 0, stream>>>(xbuf, Wk_i, bk + i * 512, nullptr,
                                           nullptr, nullptr, kbuf, M_, 512, 512, 0.f);
    gemm_kernel<0><<<gg, 256, 0, stream>>>(xbuf, Wv_i, bv + i * 512, nullptr,
                                           nullptr, nullptr, vbuf, M_, 512, 512, 0.f);

    // JAX RNG: layer key = threefry(key(42)=(0,42), (0,i));
    // split (partitionable/foldlike): k2 = threefry(layer_key, (0,1))
    uint32_t lk0, lk1, k20, k21;
    threefry2x32(0u, 42u, 0u, (uint32_t)i, &lk0, &lk1);
    threefry2x32(lk0, lk1, 0u, 1u, &k20, &k21);
    idx_kernel<<<ceil_div(L * U, 256), 256, 0, stream>>>(d_idx, L, U, k20, k21);

    sparse_m_kernel<<<ceil_div(B * NH * L * 64, 256), 256, 0, stream>>>(
        qbuf, kbuf, d_idx, d_M, B, L, U);
    topk_kernel<<<B * NH, 256, 0, stream>>>(d_M, d_Mtop, L, U);
    vmean_kernel<<<B * NH, 256, 0, stream>>>(vbuf, d_vmean, B, L);
    fill_ctx_kernel<<<ceil_div(B * L * D_MODEL, 256), 256, 0, stream>>>(
        d_vmean, obuf, B, L);
    attn_kernel<<<dim3(U, B * NH), 256, 0, stream>>>(qbuf, kbuf, vbuf, d_Mtop,
                                                     obuf, B, L, U);

    // x = x + o@Wo^T + bo ; LN1
    gemm_kernel<2><<<gg, 256, 0, stream>>>(obuf, Wo_i, bo + i * 512, xbuf,
                                           nullptr, nullptr, ebuf, M_, 512, 512, 0.f);
    ln_kernel<<<M_, 256, 0, stream>>>(ebuf, ln1_g + i * 512, ln1_b + i * 512, xbuf);

    // FF: h = gelu(x@w1^T+b1); x = LN2(x + h@w2^T+b2)
    gemm_kernel<1><<<gg, 256, 0, stream>>>(xbuf, w1_i, ff_b1 + i * 512, nullptr,
                                           nullptr, nullptr, obuf, M_, 512, 512, 0.f);
    gemm_kernel<2><<<gg, 256, 0, stream>>>(obuf, w2_i, ff_b2 + i * 512, xbuf,
                                           nullptr, nullptr, ebuf, M_, 512, 512, 0.f);
    ln_kernel<<<M_, 256, 0, stream>>>(ebuf, ln2_g + i * 512, ln2_b + i * 512, xbuf);

    if (i < EL - 1) {
      // conv_distill: im2col -> GEMM(K=1536, fused bias+bn+elu) -> maxpool
      im2col_kernel<<<ceil_div(B * L * 1536, 256), 256, 0, stream>>>(xbuf, im2c, B, L);
      gemm_kernel<3><<<gg, 256, 0, stream>>>(
          im2c, cv_w + (size_t)i * 512 * 1536, cv_b + i * 512, nullptr,
          bn_g + i * 512, bn_b + i * 512, ebuf, M_, 512, 1536, inv_s);
      maxpool_kernel<<<ceil_div(B * (L / 2) * D_MODEL, 256), 256, 0, stream>>>(
          ebuf, xbuf, B, L);
      L /= 2;
    }
  }

  // final layer norm -> d_out
  ln_kernel<<<B * L, 256, 0, stream>>>(xbuf, norm_g, norm_b, (float*)d_out);
}